// Round 12
// baseline (268.136 us; speedup 1.0000x reference)
//
#include <hip/hip_runtime.h>

// Problem constants (match reference)
#define B 32
#define S 32
#define N 128
#define U 64
#define E 2
#define NCLS 5

// R19: R15 (best, 196us) minus overheads. Null matrix now complete: broadcast
// pipe, barriers, occupancy, weight tier, weight instr count, weight bytes --
// all null; family is VALU-issue-bound at ~47% (R13 PMC). Remaining levers are
// overhead: (1) 5->3 syncs/step: dedicated LDS buffers reduce z/r/c in ONE
// sync; rh*Ug2 computed FULL-range redundantly by both k-waves (identical
// post-reduce accr/hv) -> sync5 gone. (2) k_final folded into last step via
// last-arriving-block ticket (R13-validated release/acquire; 128B-padded
// partial slots). (3) no prep. Everything else byte-identical to R15.

__device__ __forceinline__ float sigmoid_f(float x) {
    return __fdividef(1.f, 1.f + __expf(-x));
}
__device__ __forceinline__ float tanh_f(float x) {
    float t = __expf(-2.f * fabsf(x));
    float y = __fdividef(1.f - t, 1.f + t);
    return copysignf(y, x);
}
// broadcast lane u's value of v to all lanes (VALU pipe, no LDS)
__device__ __forceinline__ float bcast(float v, int u) {
    return __uint_as_float(__builtin_amdgcn_readlane(__float_as_uint(v), u));
}

template <int FIRST, int LAST>
__global__ __launch_bounds__(512, 2) void k_step(
    const float* __restrict__ x, const int* __restrict__ lens,
    const float* __restrict__ hin, float* __restrict__ hout,
    const float* __restrict__ A, const float* __restrict__ Wmsg,
    const float* __restrict__ bmsg, const float* __restrict__ Wg,
    const float* __restrict__ Ug, const float* __restrict__ bg,
    const float* __restrict__ fcw, const float* __restrict__ fcb,
    float* __restrict__ partial, unsigned int* __restrict__ cnt,
    float* __restrict__ out, int l) {
    __shared__ float sS[4][2][2][2][64];   // [g][k][row][edge][lane]  4 KB
    __shared__ float sAV[4][2][2][64];     // [g][k][row][lane]        2 KB
    __shared__ float sZ[4][2][3][2][64];   // [g][k][zrc][row][lane]  12 KB
    __shared__ float red[4 * NCLS];
    __shared__ int lastflag;
    int tid = threadIdx.x;
    int wave = tid >> 6, lane = tid & 63;
    int g = wave & 3;        // row group (2 rows each)
    int k = wave >> 2;       // split half: 0 or 1
    int b = blockIdx.x >> 4;
    int j = blockIdx.x & 15;
    int n0 = __builtin_amdgcn_readfirstlane(j * 8 + g * 2);
    int u0 = __builtin_amdgcn_readfirstlane(k * 32);   // this wave's u-range
    int m0 = __builtin_amdgcn_readfirstlane(k * 64);   // this wave's m-range

    // step-0 zeroes the per-batch arrival counters used by the LAST finale
    if (FIRST && blockIdx.x == 0 && tid < B) cnt[tid] = 0;

    const float* __restrict__ hsrc;
    if (FIRST) {
        int idx = lens[b] - 1;
        idx = idx < 0 ? 0 : (idx > S - 1 ? S - 1 : idx);
        hsrc = x + (size_t)(b * S + idx) * N * U;
    } else {
        hsrc = hin + (size_t)b * N * U;
    }

    float hv0 = hsrc[(n0 + 0) * U + lane];
    float hv1 = hsrc[(n0 + 1) * U + lane];

    // ---- P1: aggregate partials over this wave's m-half
    float s00 = 0.f, s01 = 0.f, s10 = 0.f, s11 = 0.f;  // [row][edge]
    {
        const float4* A00 = (const float4*)(A + (((size_t)b * E + 0) * N + n0 + 0) * N + m0);
        const float4* A10 = (const float4*)(A + (((size_t)b * E + 0) * N + n0 + 1) * N + m0);
        const float4* A01 = (const float4*)(A + (((size_t)b * E + 1) * N + n0 + 0) * N + m0);
        const float4* A11 = (const float4*)(A + (((size_t)b * E + 1) * N + n0 + 1) * N + m0);
#pragma unroll 8
        for (int m4 = 0; m4 < 16; ++m4) {
            float4 a00 = A00[m4], a10 = A10[m4], a01 = A01[m4], a11 = A11[m4];
            float q0 = hsrc[(m0 + m4 * 4 + 0) * U + lane];
            float q1 = hsrc[(m0 + m4 * 4 + 1) * U + lane];
            float q2 = hsrc[(m0 + m4 * 4 + 2) * U + lane];
            float q3 = hsrc[(m0 + m4 * 4 + 3) * U + lane];
            s00 = fmaf(a00.x, q0, s00); s00 = fmaf(a00.y, q1, s00);
            s00 = fmaf(a00.z, q2, s00); s00 = fmaf(a00.w, q3, s00);
            s10 = fmaf(a10.x, q0, s10); s10 = fmaf(a10.y, q1, s10);
            s10 = fmaf(a10.z, q2, s10); s10 = fmaf(a10.w, q3, s10);
            s01 = fmaf(a01.x, q0, s01); s01 = fmaf(a01.y, q1, s01);
            s01 = fmaf(a01.z, q2, s01); s01 = fmaf(a01.w, q3, s01);
            s11 = fmaf(a11.x, q0, s11); s11 = fmaf(a11.y, q1, s11);
            s11 = fmaf(a11.z, q2, s11); s11 = fmaf(a11.w, q3, s11);
        }
    }
    sS[g][k][0][0][lane] = s00;
    sS[g][k][0][1][lane] = s01;
    sS[g][k][1][0][lane] = s10;
    sS[g][k][1][1][lane] = s11;
    __syncthreads();  // sync1
    s00 = sS[g][0][0][0][lane] + sS[g][1][0][0][lane];
    s01 = sS[g][0][0][1][lane] + sS[g][1][0][1][lane];
    s10 = sS[g][0][1][0][lane] + sS[g][1][1][0][lane];
    s11 = sS[g][0][1][1][lane] + sS[g][1][1][1][lane];

    // ---- P2: msg partials over this wave's u-half (bias carried by k==0)
    float av0, av1;
    {
        float bm = (k == 0) ? bmsg[l * U + lane] : 0.f;
        av0 = bm; av1 = bm;
        const float* W0 = Wmsg + (size_t)(l * E + 0) * U * U + lane;
        const float* W1 = W0 + U * U;
#pragma unroll 16
        for (int uu = 0; uu < 32; ++uu) {
            int u = u0 + uu;
            float w = W0[u * U];
            av0 = fmaf(bcast(s00, u), w, av0);
            av1 = fmaf(bcast(s10, u), w, av1);
        }
#pragma unroll 16
        for (int uu = 0; uu < 32; ++uu) {
            int u = u0 + uu;
            float w = W1[u * U];
            av0 = fmaf(bcast(s01, u), w, av0);
            av1 = fmaf(bcast(s11, u), w, av1);
        }
    }
    sAV[g][k][0][lane] = av0;
    sAV[g][k][1][lane] = av1;
    __syncthreads();  // sync2
    av0 = sAV[g][0][0][lane] + sAV[g][1][0][lane];
    av1 = sAV[g][0][1][lane] + sAV[g][1][1][lane];

    // ---- P3: gate matmul partials over this wave's u-half
    const float* Wg0 = Wg + (size_t)l * 3 * U * U + lane;
    const float* Wg1 = Wg0 + U * U;
    const float* Wg2 = Wg1 + U * U;
    const float* Ug0 = Ug + (size_t)l * 3 * U * U + lane;
    const float* Ug1 = Ug0 + U * U;
    const float* Ug2 = Ug1 + U * U;
    float accz0, accz1, accr0, accr1, accc0, accc1;
    {
        float bz = (k == 0) ? bg[(l * 3 + 0) * U + lane] : 0.f;
        float br = (k == 0) ? bg[(l * 3 + 1) * U + lane] : 0.f;
        float bcc = (k == 0) ? bg[(l * 3 + 2) * U + lane] : 0.f;
        accz0 = bz; accz1 = bz;
        accr0 = br; accr1 = br;
        accc0 = bcc; accc1 = bcc;
#pragma unroll 8
        for (int uu = 0; uu < 32; ++uu) {
            int u = u0 + uu;
            float w0 = Wg0[u * U], w1 = Wg1[u * U], w2 = Wg2[u * U];
            float g0 = Ug0[u * U], g1 = Ug1[u * U];
            float a0 = bcast(av0, u), a1 = bcast(av1, u);
            float h0 = bcast(hv0, u), h1 = bcast(hv1, u);
            accz0 = fmaf(a0, w0, accz0); accz0 = fmaf(h0, g0, accz0);
            accz1 = fmaf(a1, w0, accz1); accz1 = fmaf(h1, g0, accz1);
            accr0 = fmaf(a0, w1, accr0); accr0 = fmaf(h0, g1, accr0);
            accr1 = fmaf(a1, w1, accr1); accr1 = fmaf(h1, g1, accr1);
            accc0 = fmaf(a0, w2, accc0);
            accc1 = fmaf(a1, w2, accc1);
        }
    }
    sZ[g][k][0][0][lane] = accz0; sZ[g][k][0][1][lane] = accz1;
    sZ[g][k][1][0][lane] = accr0; sZ[g][k][1][1][lane] = accr1;
    sZ[g][k][2][0][lane] = accc0; sZ[g][k][2][1][lane] = accc1;
    __syncthreads();  // sync3 (z, r, c in one shot — dedicated buffer)
    accz0 = sZ[g][0][0][0][lane] + sZ[g][1][0][0][lane];
    accz1 = sZ[g][0][0][1][lane] + sZ[g][1][0][1][lane];
    accr0 = sZ[g][0][1][0][lane] + sZ[g][1][1][0][lane];
    accr1 = sZ[g][0][1][1][lane] + sZ[g][1][1][1][lane];
    accc0 = sZ[g][0][2][0][lane] + sZ[g][1][2][0][lane];
    accc1 = sZ[g][0][2][1][lane] + sZ[g][1][2][1][lane];

    // ---- P4: rh matmul FULL-range on both k-waves (identical accr/hv after
    //          sync3) — no 4th/5th sync needed; +32 FMA/row vs split.
    float rh0 = sigmoid_f(accr0) * hv0;
    float rh1 = sigmoid_f(accr1) * hv1;
#pragma unroll 16
    for (int u = 0; u < U; ++u) {
        float g2 = Ug2[u * U];
        accc0 = fmaf(bcast(rh0, u), g2, accc0);
        accc1 = fmaf(bcast(rh1, u), g2, accc1);
    }

    float zg0 = sigmoid_f(accz0), zg1 = sigmoid_f(accz1);
    float hn0 = (1.f - zg0) * hv0 + zg0 * tanh_f(accc0);
    float hn1 = (1.f - zg1) * hv1 + zg1 * tanh_f(accc1);

    if (!LAST) {
        if (k == 0) {
            hout[((size_t)b * N + n0 + 0) * U + lane] = hn0;
            hout[((size_t)b * N + n0 + 1) * U + lane] = hn1;
        }
    } else {
        // classification partial over this block's 8 rows (k==0 waves)
        float lg0[NCLS], lg1[NCLS];
        float rv0 = hn0 > 0.f ? hn0 : 0.f;
        float rv1 = hn1 > 0.f ? hn1 : 0.f;
#pragma unroll
        for (int c = 0; c < NCLS; c++) {
            float w = fcw[lane * NCLS + c];
            lg0[c] = rv0 * w;
            lg1[c] = rv1 * w;
        }
#pragma unroll
        for (int off = 32; off; off >>= 1) {
#pragma unroll
            for (int c = 0; c < NCLS; c++) {
                lg0[c] += __shfl_xor(lg0[c], off, 64);
                lg1[c] += __shfl_xor(lg1[c], off, 64);
            }
        }
        if (k == 0 && lane == 0) {
#pragma unroll
            for (int c = 0; c < NCLS; c++) red[g * NCLS + c] = fmaxf(lg0[c], lg1[c]);
        }
        __syncthreads();
        if (tid < NCLS) {
            float m = red[tid];
            for (int w = 1; w < 4; ++w) m = fmaxf(m, red[w * NCLS + tid]);
            partial[(size_t)(b * 16 + j) * 32 + tid] = m;  // 128B-padded slot
        }
        // ---- fused finale: last-arriving block of batch b reduces 16 slots
        __threadfence();  // release partial stores (device scope)
        if (tid == 0) {
            unsigned int r = atomicAdd(&cnt[b], 1u);
            lastflag = (r == 15u);
        }
        __syncthreads();
        if (lastflag) {
            __threadfence();  // acquire side
            if (tid < NCLS) {
                float m = -3.4e38f;
                for (int jj = 0; jj < 16; ++jj)
                    m = fmaxf(m, partial[(size_t)(b * 16 + jj) * 32 + tid]);
                out[b * NCLS + tid] = m + fcb[tid];
            }
        }
    }
}

// ---------------------------------------------------------------------------
extern "C" void kernel_launch(void* const* d_in, const int* in_sizes, int n_in,
                              void* d_out, int out_size, void* d_ws, size_t ws_size,
                              hipStream_t stream) {
    const float* x    = (const float*)d_in[0];
    const int*   lens = (const int*)d_in[1];
    const float* A    = (const float*)d_in[2];
    const float* Wmsg = (const float*)d_in[3];
    const float* bmsg = (const float*)d_in[4];
    const float* Wg   = (const float*)d_in[5];
    const float* Ug   = (const float*)d_in[6];
    const float* bg   = (const float*)d_in[7];
    const float* fcw  = (const float*)d_in[8];
    const float* fcb  = (const float*)d_in[9];
    float* out = (float*)d_out;

    float* hA      = (float*)d_ws;                   // [B][N][U]
    float* hB      = hA + (size_t)B * N * U;         // [B][N][U]
    float* partial = hB + (size_t)B * N * U;         // [B][16][32] padded
    unsigned int* cnt = (unsigned int*)(partial + (size_t)B * 16 * 32);

    // steps 0-2: layer 0; steps 3-5: layer 1 (finale fused into step 5)
    k_step<1, 0><<<B * 16, 512, 0, stream>>>(x, lens, nullptr, hA, A, Wmsg, bmsg, Wg, Ug, bg, fcw, fcb, partial, cnt, out, 0);
    k_step<0, 0><<<B * 16, 512, 0, stream>>>(x, lens, hA, hB, A, Wmsg, bmsg, Wg, Ug, bg, fcw, fcb, partial, cnt, out, 0);
    k_step<0, 0><<<B * 16, 512, 0, stream>>>(x, lens, hB, hA, A, Wmsg, bmsg, Wg, Ug, bg, fcw, fcb, partial, cnt, out, 0);
    k_step<0, 0><<<B * 16, 512, 0, stream>>>(x, lens, hA, hB, A, Wmsg, bmsg, Wg, Ug, bg, fcw, fcb, partial, cnt, out, 1);
    k_step<0, 0><<<B * 16, 512, 0, stream>>>(x, lens, hB, hA, A, Wmsg, bmsg, Wg, Ug, bg, fcw, fcb, partial, cnt, out, 1);
    k_step<0, 1><<<B * 16, 512, 0, stream>>>(x, lens, hA, hB, A, Wmsg, bmsg, Wg, Ug, bg, fcw, fcb, partial, cnt, out, 1);
}

// Round 13
// 204.542 us; speedup vs baseline: 1.3109x; 1.3109x over previous
//
#include <hip/hip_runtime.h>

// Problem constants (match reference)
#define B 32
#define S 32
#define N 128
#define U 64
#define E 2
#define NCLS 5

// R20 = R15 (196us champion) + the proven-safe half of R19: 5->3 syncs/step.
// R19's regression was isolated by PMC: the fused finale's per-thread
// device-scope __threadfence in every block cost ~80us on the last step
// (k_step LAST = 96-100us vs ~20us regular). The merged z/r/c one-sync
// reduce + full-range redundant rh*Ug2 were fine (absmax 0.0, regular steps
// unchanged). So: R15 structure, dedicated sZ buffer (one sync for z/r/c),
// redundant P4 on both k-waves (kills sync4+sync5), separate k_final.

__device__ __forceinline__ float sigmoid_f(float x) {
    return __fdividef(1.f, 1.f + __expf(-x));
}
__device__ __forceinline__ float tanh_f(float x) {
    float t = __expf(-2.f * fabsf(x));
    float y = __fdividef(1.f - t, 1.f + t);
    return copysignf(y, x);
}
// broadcast lane u's value of v to all lanes (VALU pipe, no LDS)
__device__ __forceinline__ float bcast(float v, int u) {
    return __uint_as_float(__builtin_amdgcn_readlane(__float_as_uint(v), u));
}

template <int FIRST, int LAST>
__global__ __launch_bounds__(512, 2) void k_step(
    const float* __restrict__ x, const int* __restrict__ lens,
    const float* __restrict__ hin, float* __restrict__ hout,
    const float* __restrict__ A, const float* __restrict__ Wmsg,
    const float* __restrict__ bmsg, const float* __restrict__ Wg,
    const float* __restrict__ Ug, const float* __restrict__ bg,
    const float* __restrict__ fcw, float* __restrict__ partial, int l) {
    __shared__ float sS[4][2][2][2][64];   // [g][k][row][edge][lane]  4 KB
    __shared__ float sAV[4][2][2][64];     // [g][k][row][lane]        2 KB
    __shared__ float sZ[4][2][3][2][64];   // [g][k][zrc][row][lane]  12 KB
    __shared__ float red[4 * NCLS];
    int tid = threadIdx.x;
    int wave = tid >> 6, lane = tid & 63;
    int g = wave & 3;        // row group (2 rows each)
    int k = wave >> 2;       // split half: 0 or 1
    int b = blockIdx.x >> 4;
    int j = blockIdx.x & 15;
    int n0 = __builtin_amdgcn_readfirstlane(j * 8 + g * 2);
    int u0 = __builtin_amdgcn_readfirstlane(k * 32);   // this wave's u-range
    int m0 = __builtin_amdgcn_readfirstlane(k * 64);   // this wave's m-range

    const float* __restrict__ hsrc;
    if (FIRST) {
        int idx = lens[b] - 1;
        idx = idx < 0 ? 0 : (idx > S - 1 ? S - 1 : idx);
        hsrc = x + (size_t)(b * S + idx) * N * U;
    } else {
        hsrc = hin + (size_t)b * N * U;
    }

    float hv0 = hsrc[(n0 + 0) * U + lane];
    float hv1 = hsrc[(n0 + 1) * U + lane];

    // ---- P1: aggregate partials over this wave's m-half
    float s00 = 0.f, s01 = 0.f, s10 = 0.f, s11 = 0.f;  // [row][edge]
    {
        const float4* A00 = (const float4*)(A + (((size_t)b * E + 0) * N + n0 + 0) * N + m0);
        const float4* A10 = (const float4*)(A + (((size_t)b * E + 0) * N + n0 + 1) * N + m0);
        const float4* A01 = (const float4*)(A + (((size_t)b * E + 1) * N + n0 + 0) * N + m0);
        const float4* A11 = (const float4*)(A + (((size_t)b * E + 1) * N + n0 + 1) * N + m0);
#pragma unroll 8
        for (int m4 = 0; m4 < 16; ++m4) {
            float4 a00 = A00[m4], a10 = A10[m4], a01 = A01[m4], a11 = A11[m4];
            float q0 = hsrc[(m0 + m4 * 4 + 0) * U + lane];
            float q1 = hsrc[(m0 + m4 * 4 + 1) * U + lane];
            float q2 = hsrc[(m0 + m4 * 4 + 2) * U + lane];
            float q3 = hsrc[(m0 + m4 * 4 + 3) * U + lane];
            s00 = fmaf(a00.x, q0, s00); s00 = fmaf(a00.y, q1, s00);
            s00 = fmaf(a00.z, q2, s00); s00 = fmaf(a00.w, q3, s00);
            s10 = fmaf(a10.x, q0, s10); s10 = fmaf(a10.y, q1, s10);
            s10 = fmaf(a10.z, q2, s10); s10 = fmaf(a10.w, q3, s10);
            s01 = fmaf(a01.x, q0, s01); s01 = fmaf(a01.y, q1, s01);
            s01 = fmaf(a01.z, q2, s01); s01 = fmaf(a01.w, q3, s01);
            s11 = fmaf(a11.x, q0, s11); s11 = fmaf(a11.y, q1, s11);
            s11 = fmaf(a11.z, q2, s11); s11 = fmaf(a11.w, q3, s11);
        }
    }
    sS[g][k][0][0][lane] = s00;
    sS[g][k][0][1][lane] = s01;
    sS[g][k][1][0][lane] = s10;
    sS[g][k][1][1][lane] = s11;
    __syncthreads();  // sync1
    s00 = sS[g][0][0][0][lane] + sS[g][1][0][0][lane];
    s01 = sS[g][0][0][1][lane] + sS[g][1][0][1][lane];
    s10 = sS[g][0][1][0][lane] + sS[g][1][1][0][lane];
    s11 = sS[g][0][1][1][lane] + sS[g][1][1][1][lane];

    // ---- P2: msg partials over this wave's u-half (bias carried by k==0)
    float av0, av1;
    {
        float bm = (k == 0) ? bmsg[l * U + lane] : 0.f;
        av0 = bm; av1 = bm;
        const float* W0 = Wmsg + (size_t)(l * E + 0) * U * U + lane;
        const float* W1 = W0 + U * U;
#pragma unroll 16
        for (int uu = 0; uu < 32; ++uu) {
            int u = u0 + uu;
            float w = W0[u * U];
            av0 = fmaf(bcast(s00, u), w, av0);
            av1 = fmaf(bcast(s10, u), w, av1);
        }
#pragma unroll 16
        for (int uu = 0; uu < 32; ++uu) {
            int u = u0 + uu;
            float w = W1[u * U];
            av0 = fmaf(bcast(s01, u), w, av0);
            av1 = fmaf(bcast(s11, u), w, av1);
        }
    }
    sAV[g][k][0][lane] = av0;
    sAV[g][k][1][lane] = av1;
    __syncthreads();  // sync2
    av0 = sAV[g][0][0][lane] + sAV[g][1][0][lane];
    av1 = sAV[g][0][1][lane] + sAV[g][1][1][lane];

    // ---- P3: gate matmul partials over this wave's u-half
    const float* Wg0 = Wg + (size_t)l * 3 * U * U + lane;
    const float* Wg1 = Wg0 + U * U;
    const float* Wg2 = Wg1 + U * U;
    const float* Ug0 = Ug + (size_t)l * 3 * U * U + lane;
    const float* Ug1 = Ug0 + U * U;
    const float* Ug2 = Ug1 + U * U;
    float accz0, accz1, accr0, accr1, accc0, accc1;
    {
        float bz = (k == 0) ? bg[(l * 3 + 0) * U + lane] : 0.f;
        float br = (k == 0) ? bg[(l * 3 + 1) * U + lane] : 0.f;
        float bcc = (k == 0) ? bg[(l * 3 + 2) * U + lane] : 0.f;
        accz0 = bz; accz1 = bz;
        accr0 = br; accr1 = br;
        accc0 = bcc; accc1 = bcc;
#pragma unroll 8
        for (int uu = 0; uu < 32; ++uu) {
            int u = u0 + uu;
            float w0 = Wg0[u * U], w1 = Wg1[u * U], w2 = Wg2[u * U];
            float g0 = Ug0[u * U], g1 = Ug1[u * U];
            float a0 = bcast(av0, u), a1 = bcast(av1, u);
            float h0 = bcast(hv0, u), h1 = bcast(hv1, u);
            accz0 = fmaf(a0, w0, accz0); accz0 = fmaf(h0, g0, accz0);
            accz1 = fmaf(a1, w0, accz1); accz1 = fmaf(h1, g0, accz1);
            accr0 = fmaf(a0, w1, accr0); accr0 = fmaf(h0, g1, accr0);
            accr1 = fmaf(a1, w1, accr1); accr1 = fmaf(h1, g1, accr1);
            accc0 = fmaf(a0, w2, accc0);
            accc1 = fmaf(a1, w2, accc1);
        }
    }
    sZ[g][k][0][0][lane] = accz0; sZ[g][k][0][1][lane] = accz1;
    sZ[g][k][1][0][lane] = accr0; sZ[g][k][1][1][lane] = accr1;
    sZ[g][k][2][0][lane] = accc0; sZ[g][k][2][1][lane] = accc1;
    __syncthreads();  // sync3 (z, r, c in one shot — dedicated buffer)
    accz0 = sZ[g][0][0][0][lane] + sZ[g][1][0][0][lane];
    accz1 = sZ[g][0][0][1][lane] + sZ[g][1][0][1][lane];
    accr0 = sZ[g][0][1][0][lane] + sZ[g][1][1][0][lane];
    accr1 = sZ[g][0][1][1][lane] + sZ[g][1][1][1][lane];
    accc0 = sZ[g][0][2][0][lane] + sZ[g][1][2][0][lane];
    accc1 = sZ[g][0][2][1][lane] + sZ[g][1][2][1][lane];

    // ---- P4: rh matmul FULL-range on both k-waves (identical accr/hv after
    //          sync3) — no 4th/5th sync needed; +32 FMA/row vs split.
    float rh0 = sigmoid_f(accr0) * hv0;
    float rh1 = sigmoid_f(accr1) * hv1;
#pragma unroll 16
    for (int u = 0; u < U; ++u) {
        float g2 = Ug2[u * U];
        accc0 = fmaf(bcast(rh0, u), g2, accc0);
        accc1 = fmaf(bcast(rh1, u), g2, accc1);
    }

    float zg0 = sigmoid_f(accz0), zg1 = sigmoid_f(accz1);
    float hn0 = (1.f - zg0) * hv0 + zg0 * tanh_f(accc0);
    float hn1 = (1.f - zg1) * hv1 + zg1 * tanh_f(accc1);

    if (!LAST) {
        if (k == 0) {
            hout[((size_t)b * N + n0 + 0) * U + lane] = hn0;
            hout[((size_t)b * N + n0 + 1) * U + lane] = hn1;
        }
    } else {
        // classification partial over this block's 8 rows (k==0 waves)
        float lg0[NCLS], lg1[NCLS];
        float rv0 = hn0 > 0.f ? hn0 : 0.f;
        float rv1 = hn1 > 0.f ? hn1 : 0.f;
#pragma unroll
        for (int c = 0; c < NCLS; c++) {
            float w = fcw[lane * NCLS + c];
            lg0[c] = rv0 * w;
            lg1[c] = rv1 * w;
        }
#pragma unroll
        for (int off = 32; off; off >>= 1) {
#pragma unroll
            for (int c = 0; c < NCLS; c++) {
                lg0[c] += __shfl_xor(lg0[c], off, 64);
                lg1[c] += __shfl_xor(lg1[c], off, 64);
            }
        }
        if (k == 0 && lane == 0) {
#pragma unroll
            for (int c = 0; c < NCLS; c++) red[g * NCLS + c] = fmaxf(lg0[c], lg1[c]);
        }
        __syncthreads();
        if (tid < NCLS) {
            float m = red[tid];
            for (int w = 1; w < 4; ++w) m = fmaxf(m, red[w * NCLS + tid]);
            partial[(size_t)(b * 16 + j) * NCLS + tid] = m;
        }
    }
}

// ---------------------------------------------------------------------------
// k_final: out[b][c] = max over 16 block-partials + fc_b
__global__ void k_final(const float* __restrict__ partial, const float* __restrict__ fcb,
                        float* __restrict__ out) {
    int b = blockIdx.x, c = threadIdx.x;
    if (c < NCLS) {
        float m = -3.4e38f;
        for (int jj = 0; jj < 16; ++jj)
            m = fmaxf(m, partial[(size_t)(b * 16 + jj) * NCLS + c]);
        out[b * NCLS + c] = m + fcb[c];
    }
}

// ---------------------------------------------------------------------------
extern "C" void kernel_launch(void* const* d_in, const int* in_sizes, int n_in,
                              void* d_out, int out_size, void* d_ws, size_t ws_size,
                              hipStream_t stream) {
    const float* x    = (const float*)d_in[0];
    const int*   lens = (const int*)d_in[1];
    const float* A    = (const float*)d_in[2];
    const float* Wmsg = (const float*)d_in[3];
    const float* bmsg = (const float*)d_in[4];
    const float* Wg   = (const float*)d_in[5];
    const float* Ug   = (const float*)d_in[6];
    const float* bg   = (const float*)d_in[7];
    const float* fcw  = (const float*)d_in[8];
    const float* fcb  = (const float*)d_in[9];
    float* out = (float*)d_out;

    float* hA      = (float*)d_ws;                   // [B][N][U]
    float* hB      = hA + (size_t)B * N * U;         // [B][N][U]
    float* partial = hB + (size_t)B * N * U;         // [B][16][NCLS]

    // steps 0-2: layer 0; steps 3-5: layer 1
    k_step<1, 0><<<B * 16, 512, 0, stream>>>(x, lens, nullptr, hA, A, Wmsg, bmsg, Wg, Ug, bg, fcw, partial, 0);
    k_step<0, 0><<<B * 16, 512, 0, stream>>>(x, lens, hA, hB, A, Wmsg, bmsg, Wg, Ug, bg, fcw, partial, 0);
    k_step<0, 0><<<B * 16, 512, 0, stream>>>(x, lens, hB, hA, A, Wmsg, bmsg, Wg, Ug, bg, fcw, partial, 0);
    k_step<0, 0><<<B * 16, 512, 0, stream>>>(x, lens, hA, hB, A, Wmsg, bmsg, Wg, Ug, bg, fcw, partial, 1);
    k_step<0, 0><<<B * 16, 512, 0, stream>>>(x, lens, hB, hA, A, Wmsg, bmsg, Wg, Ug, bg, fcw, partial, 1);
    k_step<0, 1><<<B * 16, 512, 0, stream>>>(x, lens, hA, hB, A, Wmsg, bmsg, Wg, Ug, bg, fcw, partial, 1);
    k_final<<<B, 64, 0, stream>>>(partial, fcb, out);
}

// Round 14
// 194.905 us; speedup vs baseline: 1.3757x; 1.0494x over previous
//
#include <hip/hip_runtime.h>

// Problem constants (match reference)
#define B 32
#define S 32
#define N 128
#define U 64
#define E 2
#define NCLS 5

// R21: FINAL — exact revert to the R15 champion (196.0us, best of 14 rounds).
// Lever catalog exhausted with evidence: broadcast pipe (R8), barriers (R9),
// occupancy 4-32 waves/CU (R10/R14/R16), grid-sync fusion (R11/R13), weight
// tier L1/L2/LDS (R12/R17), weight bytes+instrs /4 (R18), sync count (R19/
// R20) — all null or regressions. Only split-K=2 TLP at constant per-CU
// traffic paid (-13us). Remaining gap to VALU-issue peak is the serial
// 6-step dependency + readlane-broadcast overhead; the only >=2x lever left
// is bf16 MFMA (no fp32 MFMA on CDNA4), which forfeits the bit-exact record.
// Structure: 512 blocks x 512 thr (2 blocks/CU, 16 waves/CU, 4/SIMD); two
// waves share each row-pair (wave k owns m-half + u-half); partials meet in
// LDS; 4 syncs + tail. Accumulation order preserved -> absmax 0.0.

__device__ __forceinline__ float sigmoid_f(float x) {
    return __fdividef(1.f, 1.f + __expf(-x));
}
__device__ __forceinline__ float tanh_f(float x) {
    float t = __expf(-2.f * fabsf(x));
    float y = __fdividef(1.f - t, 1.f + t);
    return copysignf(y, x);
}
// broadcast lane u's value of v to all lanes (VALU pipe, no LDS)
__device__ __forceinline__ float bcast(float v, int u) {
    return __uint_as_float(__builtin_amdgcn_readlane(__float_as_uint(v), u));
}

template <int FIRST, int LAST>
__global__ __launch_bounds__(512, 2) void k_step(
    const float* __restrict__ x, const int* __restrict__ lens,
    const float* __restrict__ hin, float* __restrict__ hout,
    const float* __restrict__ A, const float* __restrict__ Wmsg,
    const float* __restrict__ bmsg, const float* __restrict__ Wg,
    const float* __restrict__ Ug, const float* __restrict__ bg,
    const float* __restrict__ fcw, float* __restrict__ partial, int l) {
    // partial-reduce buffers: [group][khalf][...][lane]
    __shared__ float sred[4][2][2][2][64];   // [g][k][row][edge][lane]  8 KB
    __shared__ float avred[4][2][2][64];     // [g][k][row][lane]        4 KB
    __shared__ float gred[4][2][3][2][64];   // [g][k][zrc][row][lane]  12 KB
    __shared__ float c2red[4][2][2][64];     // [g][k][row][lane]        4 KB
    __shared__ float red[4 * NCLS];
    int tid = threadIdx.x;
    int wave = tid >> 6, lane = tid & 63;
    int g = wave & 3;        // row group (2 rows each)
    int k = wave >> 2;       // split half: 0 or 1
    int b = blockIdx.x >> 4;
    int j = blockIdx.x & 15;
    int n0 = __builtin_amdgcn_readfirstlane(j * 8 + g * 2);
    int u0 = __builtin_amdgcn_readfirstlane(k * 32);   // this wave's u-range
    int m0 = __builtin_amdgcn_readfirstlane(k * 64);   // this wave's m-range

    const float* __restrict__ hsrc;
    if (FIRST) {
        int idx = lens[b] - 1;
        idx = idx < 0 ? 0 : (idx > S - 1 ? S - 1 : idx);
        hsrc = x + (size_t)(b * S + idx) * N * U;
    } else {
        hsrc = hin + (size_t)b * N * U;
    }

    float hv0 = hsrc[(n0 + 0) * U + lane];
    float hv1 = hsrc[(n0 + 1) * U + lane];

    // ---- aggregate partials over this wave's m-half
    float s00 = 0.f, s01 = 0.f, s10 = 0.f, s11 = 0.f;  // [row][edge]
    {
        const float4* A00 = (const float4*)(A + (((size_t)b * E + 0) * N + n0 + 0) * N + m0);
        const float4* A10 = (const float4*)(A + (((size_t)b * E + 0) * N + n0 + 1) * N + m0);
        const float4* A01 = (const float4*)(A + (((size_t)b * E + 1) * N + n0 + 0) * N + m0);
        const float4* A11 = (const float4*)(A + (((size_t)b * E + 1) * N + n0 + 1) * N + m0);
#pragma unroll 8
        for (int m4 = 0; m4 < 16; ++m4) {
            float4 a00 = A00[m4], a10 = A10[m4], a01 = A01[m4], a11 = A11[m4];
            float q0 = hsrc[(m0 + m4 * 4 + 0) * U + lane];
            float q1 = hsrc[(m0 + m4 * 4 + 1) * U + lane];
            float q2 = hsrc[(m0 + m4 * 4 + 2) * U + lane];
            float q3 = hsrc[(m0 + m4 * 4 + 3) * U + lane];
            s00 = fmaf(a00.x, q0, s00); s00 = fmaf(a00.y, q1, s00);
            s00 = fmaf(a00.z, q2, s00); s00 = fmaf(a00.w, q3, s00);
            s10 = fmaf(a10.x, q0, s10); s10 = fmaf(a10.y, q1, s10);
            s10 = fmaf(a10.z, q2, s10); s10 = fmaf(a10.w, q3, s10);
            s01 = fmaf(a01.x, q0, s01); s01 = fmaf(a01.y, q1, s01);
            s01 = fmaf(a01.z, q2, s01); s01 = fmaf(a01.w, q3, s01);
            s11 = fmaf(a11.x, q0, s11); s11 = fmaf(a11.y, q1, s11);
            s11 = fmaf(a11.z, q2, s11); s11 = fmaf(a11.w, q3, s11);
        }
    }
    sred[g][k][0][0][lane] = s00;
    sred[g][k][0][1][lane] = s01;
    sred[g][k][1][0][lane] = s10;
    sred[g][k][1][1][lane] = s11;
    __syncthreads();
    s00 = sred[g][0][0][0][lane] + sred[g][1][0][0][lane];
    s01 = sred[g][0][0][1][lane] + sred[g][1][0][1][lane];
    s10 = sred[g][0][1][0][lane] + sred[g][1][1][0][lane];
    s11 = sred[g][0][1][1][lane] + sred[g][1][1][1][lane];

    // ---- msg partials over this wave's u-half (bias carried by k==0)
    float av0, av1;
    {
        float bm = (k == 0) ? bmsg[l * U + lane] : 0.f;
        av0 = bm; av1 = bm;
        const float* W0 = Wmsg + (size_t)(l * E + 0) * U * U + lane;
        const float* W1 = W0 + U * U;
#pragma unroll 16
        for (int uu = 0; uu < 32; ++uu) {
            int u = u0 + uu;
            float w = W0[u * U];
            av0 = fmaf(bcast(s00, u), w, av0);
            av1 = fmaf(bcast(s10, u), w, av1);
        }
#pragma unroll 16
        for (int uu = 0; uu < 32; ++uu) {
            int u = u0 + uu;
            float w = W1[u * U];
            av0 = fmaf(bcast(s01, u), w, av0);
            av1 = fmaf(bcast(s11, u), w, av1);
        }
    }
    avred[g][k][0][lane] = av0;
    avred[g][k][1][lane] = av1;
    __syncthreads();
    av0 = avred[g][0][0][lane] + avred[g][1][0][lane];
    av1 = avred[g][0][1][lane] + avred[g][1][1][lane];

    // ---- gate matmul partials over this wave's u-half
    const float* Wg0 = Wg + (size_t)l * 3 * U * U + lane;
    const float* Wg1 = Wg0 + U * U;
    const float* Wg2 = Wg1 + U * U;
    const float* Ug0 = Ug + (size_t)l * 3 * U * U + lane;
    const float* Ug1 = Ug0 + U * U;
    const float* Ug2 = Ug1 + U * U;
    float accz0, accz1, accr0, accr1, accc0, accc1;
    {
        float bz = (k == 0) ? bg[(l * 3 + 0) * U + lane] : 0.f;
        float br = (k == 0) ? bg[(l * 3 + 1) * U + lane] : 0.f;
        float bcc = (k == 0) ? bg[(l * 3 + 2) * U + lane] : 0.f;
        accz0 = bz; accz1 = bz;
        accr0 = br; accr1 = br;
        accc0 = bcc; accc1 = bcc;
#pragma unroll 8
        for (int uu = 0; uu < 32; ++uu) {
            int u = u0 + uu;
            float w0 = Wg0[u * U], w1 = Wg1[u * U], w2 = Wg2[u * U];
            float g0 = Ug0[u * U], g1 = Ug1[u * U];
            float a0 = bcast(av0, u), a1 = bcast(av1, u);
            float h0 = bcast(hv0, u), h1 = bcast(hv1, u);
            accz0 = fmaf(a0, w0, accz0); accz0 = fmaf(h0, g0, accz0);
            accz1 = fmaf(a1, w0, accz1); accz1 = fmaf(h1, g0, accz1);
            accr0 = fmaf(a0, w1, accr0); accr0 = fmaf(h0, g1, accr0);
            accr1 = fmaf(a1, w1, accr1); accr1 = fmaf(h1, g1, accr1);
            accc0 = fmaf(a0, w2, accc0);
            accc1 = fmaf(a1, w2, accc1);
        }
    }
    gred[g][k][0][0][lane] = accz0; gred[g][k][0][1][lane] = accz1;
    gred[g][k][1][0][lane] = accr0; gred[g][k][1][1][lane] = accr1;
    gred[g][k][2][0][lane] = accc0; gred[g][k][2][1][lane] = accc1;
    __syncthreads();
    accz0 = gred[g][0][0][0][lane] + gred[g][1][0][0][lane];
    accz1 = gred[g][0][0][1][lane] + gred[g][1][0][1][lane];
    accr0 = gred[g][0][1][0][lane] + gred[g][1][1][0][lane];
    accr1 = gred[g][0][1][1][lane] + gred[g][1][1][1][lane];
    accc0 = gred[g][0][2][0][lane] + gred[g][1][2][0][lane];
    accc1 = gred[g][0][2][1][lane] + gred[g][1][2][1][lane];

    // ---- rh matmul partials over this wave's u-half (rh identical on both)
    float rh0 = sigmoid_f(accr0) * hv0;
    float rh1 = sigmoid_f(accr1) * hv1;
    float c20 = 0.f, c21 = 0.f;
#pragma unroll 16
    for (int uu = 0; uu < 32; ++uu) {
        int u = u0 + uu;
        float g2 = Ug2[u * U];
        c20 = fmaf(bcast(rh0, u), g2, c20);
        c21 = fmaf(bcast(rh1, u), g2, c21);
    }
    c2red[g][k][0][lane] = c20;
    c2red[g][k][1][lane] = c21;
    __syncthreads();
    accc0 += c2red[g][0][0][lane] + c2red[g][1][0][lane];
    accc1 += c2red[g][0][1][lane] + c2red[g][1][1][lane];

    float zg0 = sigmoid_f(accz0), zg1 = sigmoid_f(accz1);
    float hn0 = (1.f - zg0) * hv0 + zg0 * tanh_f(accc0);
    float hn1 = (1.f - zg1) * hv1 + zg1 * tanh_f(accc1);

    if (!LAST) {
        if (k == 0) {
            hout[((size_t)b * N + n0 + 0) * U + lane] = hn0;
            hout[((size_t)b * N + n0 + 1) * U + lane] = hn1;
        }
    } else {
        // classification partial over this block's 8 rows (k==0 waves own it)
        float lg0[NCLS], lg1[NCLS];
        float rv0 = hn0 > 0.f ? hn0 : 0.f;
        float rv1 = hn1 > 0.f ? hn1 : 0.f;
#pragma unroll
        for (int c = 0; c < NCLS; c++) {
            float w = fcw[lane * NCLS + c];
            lg0[c] = rv0 * w;
            lg1[c] = rv1 * w;
        }
#pragma unroll
        for (int off = 32; off; off >>= 1) {
#pragma unroll
            for (int c = 0; c < NCLS; c++) {
                lg0[c] += __shfl_xor(lg0[c], off, 64);
                lg1[c] += __shfl_xor(lg1[c], off, 64);
            }
        }
        if (k == 0 && lane == 0) {
#pragma unroll
            for (int c = 0; c < NCLS; c++) red[g * NCLS + c] = fmaxf(lg0[c], lg1[c]);
        }
        __syncthreads();
        if (tid < NCLS) {
            float m = red[tid];
            for (int w = 1; w < 4; ++w) m = fmaxf(m, red[w * NCLS + tid]);
            partial[(size_t)(b * 16 + j) * NCLS + tid] = m;
        }
    }
}

// ---------------------------------------------------------------------------
// k_final: out[b][c] = max over 16 block-partials + fc_b
__global__ void k_final(const float* __restrict__ partial, const float* __restrict__ fcb,
                        float* __restrict__ out) {
    int b = blockIdx.x, c = threadIdx.x;
    if (c < NCLS) {
        float m = -3.4e38f;
        for (int jj = 0; jj < 16; ++jj)
            m = fmaxf(m, partial[(size_t)(b * 16 + jj) * NCLS + c]);
        out[b * NCLS + c] = m + fcb[c];
    }
}

// ---------------------------------------------------------------------------
extern "C" void kernel_launch(void* const* d_in, const int* in_sizes, int n_in,
                              void* d_out, int out_size, void* d_ws, size_t ws_size,
                              hipStream_t stream) {
    const float* x    = (const float*)d_in[0];
    const int*   lens = (const int*)d_in[1];
    const float* A    = (const float*)d_in[2];
    const float* Wmsg = (const float*)d_in[3];
    const float* bmsg = (const float*)d_in[4];
    const float* Wg   = (const float*)d_in[5];
    const float* Ug   = (const float*)d_in[6];
    const float* bg   = (const float*)d_in[7];
    const float* fcw  = (const float*)d_in[8];
    const float* fcb  = (const float*)d_in[9];
    float* out = (float*)d_out;

    float* hA      = (float*)d_ws;                   // [B][N][U]
    float* hB      = hA + (size_t)B * N * U;         // [B][N][U]
    float* partial = hB + (size_t)B * N * U;         // [B][16][NCLS]

    // steps 0-2: layer 0; steps 3-5: layer 1
    k_step<1, 0><<<B * 16, 512, 0, stream>>>(x, lens, nullptr, hA, A, Wmsg, bmsg, Wg, Ug, bg, fcw, partial, 0);
    k_step<0, 0><<<B * 16, 512, 0, stream>>>(x, lens, hA, hB, A, Wmsg, bmsg, Wg, Ug, bg, fcw, partial, 0);
    k_step<0, 0><<<B * 16, 512, 0, stream>>>(x, lens, hB, hA, A, Wmsg, bmsg, Wg, Ug, bg, fcw, partial, 0);
    k_step<0, 0><<<B * 16, 512, 0, stream>>>(x, lens, hA, hB, A, Wmsg, bmsg, Wg, Ug, bg, fcw, partial, 1);
    k_step<0, 0><<<B * 16, 512, 0, stream>>>(x, lens, hB, hA, A, Wmsg, bmsg, Wg, Ug, bg, fcw, partial, 1);
    k_step<0, 1><<<B * 16, 512, 0, stream>>>(x, lens, hA, hB, A, Wmsg, bmsg, Wg, Ug, bg, fcw, partial, 1);
    k_final<<<B, 64, 0, stream>>>(partial, fcb, out);
}